// Round 15
// baseline (141.021 us; speedup 1.0000x reference)
//
#include <hip/hip_runtime.h>
#include <stdint.h>

#define N_BOX 1024
#define C_CLS 80
#define B_IMG 4
#define K_PER 100
#define K_TOT 300
#define NEGF  (-1e30f)
#define NWORD 16                 // 1024 bits / 64
#define NCAND (C_CLS * K_PER)    // 8000 candidates per image
#define M_SEL 8192               // flat-index packing base for final top-k
#define KPAD  1088               // 1024 + 64 swizzle pad

// workspace layout (bytes) — 2,091,008 total (proven footprint)
#define OFF_SCOREST 0            // [B][C][N] f32          1,310,720
#define OFF_MASKS   1310720     // [B][N][NWORD] u64        524,288
#define OFF_WSCORE  1835008     // [B*C][K_PER] f32         128,000
#define OFF_WSIDX   1963008     // [B*C][K_PER] i32         128,000

typedef unsigned long long u64;
typedef unsigned int u32;

// LDS bank swizzle for u64 key array: bank16 rotates per 16-element group.
__device__ __forceinline__ int swz(int i) { return i + (i >> 4); }

// ---- monotone float <-> ordered-uint mapping (total order, bit-exact) ----
__device__ __forceinline__ u32 ford(float f) {
    u32 u = __float_as_uint(f);
    return (u & 0x80000000u) ? ~u : (u | 0x80000000u);
}
__device__ __forceinline__ float funord(u32 o) {
    u32 u = (o & 0x80000000u) ? (o ^ 0x80000000u) : ~o;
    return __uint_as_float(u);
}

// ---------------------------------------------------------------------------
// Kernel 1 (fused prep, proven verbatim): blocks [0,256) = IoU bitmask
// matrix (hoisted canonicalization); blocks [256,1536) = transpose.
// ---------------------------------------------------------------------------
__global__ __launch_bounds__(256) void prep_kernel(
        const float* __restrict__ scores,   // [B, N, C]
        const float* __restrict__ boxes,    // [B, N, 1, 4]
        u64*   __restrict__ masks,          // [B, N, NWORD]
        float* __restrict__ scoresT)        // [B, C, N]
{
    __shared__ float4 bx[N_BOX];            // canonical y1,x1,y2,x2 (16 KB)
    __shared__ float  ar[N_BOX];            // area (4 KB)
    const int tid = threadIdx.x;

    if (blockIdx.x < 256) {
        const int b  = blockIdx.x >> 6;
        const int rg = blockIdx.x & 63;
        for (int n = tid; n < N_BOX; n += 256) {
            float4 v = ((const float4*)boxes)[b * N_BOX + n];
            {
#pragma clang fp contract(off)
                float y1 = fminf(v.x, v.z), y2 = fmaxf(v.x, v.z);
                float x1 = fminf(v.y, v.w), x2 = fmaxf(v.y, v.w);
                bx[n] = make_float4(y1, x1, y2, x2);
                ar[n] = (y2 - y1) * (x2 - x1);
            }
        }
        __syncthreads();

        const int r = tid >> 4;
        const int w = tid & 15;
        const int i = rg * 16 + r;
        const float4 a = bx[i];
        const float area_a = ar[i];
        u64 m = 0;
        const int j0 = w * 64;
        for (int jj = 0; jj < 64; ++jj) {
            int j = j0 + jj;
            float4 q = bx[j];
            {
#pragma clang fp contract(off)
                float ih = fminf(a.z, q.z) - fmaxf(a.x, q.x); ih = fmaxf(ih, 0.0f);
                float iw = fminf(a.w, q.w) - fmaxf(a.y, q.y); iw = fmaxf(iw, 0.0f);
                float inter = ih * iw;
                float uni = fmaxf(area_a + ar[j] - inter, 1e-12f);
                if (j != i && (inter / uni) > 0.5f) m |= (1ull << jj);
            }
        }
        masks[((size_t)(b * N_BOX + i)) * NWORD + w] = m;
    } else {
        float* tile = (float*)bx;               // [16][17]
        const int t = blockIdx.x - 256;
        const int b  = t / 320;
        const int rm = t % 320;
        const int n0 = (rm / 5) * 16;
        const int c0 = (rm % 5) * 16;
        const int r = tid >> 4, cc = tid & 15;
        tile[r * 17 + cc] = scores[(size_t)(b * N_BOX + n0 + r) * C_CLS + c0 + cc];
        __syncthreads();
        scoresT[(size_t)(b * C_CLS + c0 + r) * N_BOX + n0 + cc] = tile[cc * 17 + r];
    }
}

// ---------------------------------------------------------------------------
// Kernel 2 (fused sort + phase-parallel greedy): one block per (image,
// class-PAIR), 512 thr. Sort: proven register/shuffle bitonic (swizzled).
// Phase A (ALL 8 waves): build all 16 per-window kill-masks in parallel
// (sup-independent!). Phase B (waves 0/4): serial sweep — ext-check vs sup,
// pure-VALU accept loop on precomputed kill-mask, batched sup row loads.
// ---------------------------------------------------------------------------
__global__ __launch_bounds__(512) void nms_classes(
        const float* __restrict__ scoresT,  // [B, C, N]
        const u64*   __restrict__ masks,    // [B, N, NWORD]
        float* __restrict__ ws_score,       // [B*C*K_PER]
        int*   __restrict__ ws_idx)         // [B*C*K_PER]
{
    __shared__ u64 key[2][KPAD];            // 17408 B (swizzled)
    __shared__ u64 killm[2][16][64];        // 16384 B — per-window kill masks
    __shared__ u64 scratch[2][4][64][NWORD];// 65536 B — per-wave row slices
    __shared__ int kept_t[2][K_PER];
    __shared__ int sh_nvalid[2], sh_kept[2];

    const int tid  = threadIdx.x;
    const int half = tid >> 8;              // 0/1 = which class of the pair
    const int lt   = tid & 255;             // half-local thread id
    const int lane = tid & 63;
    const int b  = blockIdx.x / (C_CLS / 2);
    const int c  = (blockIdx.x % (C_CLS / 2)) * 2 + half;

    if (lt == 0) { sh_nvalid[half] = 0; sh_kept[half] = 0; }
    __syncthreads();

    // ---- load: thread lt owns elements v = lt*4+q (coalesced float4) ----
    u64 r[4];
    {
        const float4 s4 = ((const float4*)(scoresT + ((size_t)(b * C_CLS + c) << 10)))[lt];
        float sv[4] = {s4.x, s4.y, s4.z, s4.w};
        int lv = 0;
        #pragma unroll
        for (int q = 0; q < 4; ++q) {
            bool valid = sv[q] > 0.001f;               // SCORE_THR
            float s = valid ? sv[q] : NEGF;
            int v = lt * 4 + q;
            r[q] = ((u64)ford(s) << 32) | (u32)(N_BOX - 1 - v);  // stable ties
            lv += valid ? 1 : 0;
        }
        if (lv) atomicAdd(&sh_nvalid[half], lv);
    }

    // ---- register/shuffle bitonic sort, descending (proven network) ----
    #define CE(a, b, d) { u64 _mx = (a) > (b) ? (a) : (b); \
                          u64 _mn = (a) > (b) ? (b) : (a); \
                          (a) = (d) ? _mx : _mn; (b) = (d) ? _mn : _mx; }
    CE(r[0], r[1], true); CE(r[2], r[3], false);

    for (int k = 4; k <= N_BOX; k <<= 1) {
        const bool d = ((lt & (k >> 2)) == 0);
        for (int j = k >> 1; j > 0; j >>= 1) {
            if (j >= 256) {                          // cross-wave: LDS stage
                __syncthreads();
                #pragma unroll
                for (int q = 0; q < 4; ++q) key[half][swz(lt * 4 + q)] = r[q];
                __syncthreads();
                const bool upper = ((lt * 4) & j) != 0;
                #pragma unroll
                for (int q = 0; q < 4; ++q) {
                    u64 pv = key[half][swz((lt * 4 + q) ^ j)];
                    u64 mx = r[q] > pv ? r[q] : pv;
                    u64 mn = r[q] > pv ? pv : r[q];
                    r[q] = (d != upper) ? mx : mn;
                }
            } else if (j >= 4) {                     // intra-wave: shuffle
                const int dl = j >> 2;
                const bool upper = (lane & dl) != 0;
                #pragma unroll
                for (int q = 0; q < 4; ++q) {
                    u64 pv = __shfl_xor(r[q], dl);
                    u64 mx = r[q] > pv ? r[q] : pv;
                    u64 mn = r[q] > pv ? pv : r[q];
                    r[q] = (d != upper) ? mx : mn;
                }
            } else if (j == 2) {
                CE(r[0], r[2], d); CE(r[1], r[3], d);
            } else {
                CE(r[0], r[1], d); CE(r[2], r[3], d);
            }
        }
    }
    #undef CE

    __syncthreads();
    #pragma unroll
    for (int q = 0; q < 4; ++q) key[half][swz(lt * 4 + q)] = r[q];
    __syncthreads();

    const u64* mrow = masks + (size_t)b * N_BOX * NWORD;
    const int w16 = lane & 15;
    const int sslot = lane >> 4;            // 0..3
    const int nvalid = sh_nvalid[half];

    // ---- PHASE A (all 8 waves): build all 16 kill-masks in parallel ----
    {
        const int wq = (tid >> 6) & 3;      // wave index within half
        for (int w = wq; w < 16; w += 4) {
            const int bt = w * 64;
            if (bt >= nvalid) break;
            u64 kv = key[half][swz(bt + lane)];
            int idx = (N_BOX - 1) - (int)(u32)(kv & 0xFFFFFFFFu);
            const int widx = idx >> 6, bidx = idx & 63;
            // prefetch this window's 64 rows into my wave's scratch slice
            #pragma unroll
            for (int p = 0; p < 16; ++p) {
                int rr = p * 4 + sslot;
                int ir = __shfl(idx, rr);
                u64 v = ((bt + rr) < nvalid) ? mrow[(size_t)ir * NWORD + w16] : 0;
                scratch[half][wq][rr][w16] = v;
            }
            __builtin_amdgcn_wave_barrier();
            // kill mask: bit rr = window-row rr suppresses my candidate
            u64 km = 0;
            #pragma unroll
            for (int rr = 0; rr < 64; ++rr)
                km |= ((scratch[half][wq][rr][widx] >> bidx) & 1ull) << rr;
            killm[half][w][lane] = km;
            __builtin_amdgcn_wave_barrier();
        }
    }
    __syncthreads();

    // ---- PHASE B (waves 0/4): serial sweep, nearly memory-free ----
    const int wv = tid >> 6;
    if (wv == 0 || wv == 4) {
        const int gh = wv >> 2;
        const int nv = sh_nvalid[gh];
        u64 sup = 0;                         // lanes 0..15 hold words
        int kept = 0;

        for (int w = 0; w < 16 && kept < K_PER; ++w) {
            const int bt = w * 64;
            if (bt >= nv) break;
            bool in = (bt + lane) < nv;
            u64 kv = key[gh][swz(bt + lane)];
            int idx = (N_BOX - 1) - (int)(u32)(kv & 0xFFFFFFFFu);
            const int widx = idx >> 6, bidx = idx & 63;
            u64 supw = __shfl(sup, widx);
            u64 pending = __ballot(in && !((supw >> bidx) & 1ull));
            if (!pending) continue;
            u64 km = killm[gh][w][lane];     // one LDS read per window
            u64 accmask = 0;

            while (pending && kept < K_PER) {
                int t0 = __ffsll((long long)pending) - 1;   // wave-uniform
                if (lane == 0) kept_t[gh][kept] = bt + t0;
                kept++;
                accmask |= (1ull << t0);
                bool kill = (km >> t0) & 1ull;
                pending &= ~(1ull << t0);
                pending &= ~__ballot(kill);
            }

            // batched sup update: 8 independent row loads per round-trip
            while (accmask) {
                int ia[8]; int n = 0;
                #pragma unroll
                for (int r2 = 0; r2 < 8; ++r2) {
                    ia[r2] = 0;
                    if (accmask) {
                        int a = __ffsll((long long)accmask) - 1;
                        accmask &= accmask - 1;
                        ia[r2] = __shfl(idx, a);
                        n = r2 + 1;
                    }
                }
                u64 vv[8];
                #pragma unroll
                for (int r2 = 0; r2 < 8; ++r2)
                    vv[r2] = (r2 < n && lane < NWORD)
                           ? mrow[(size_t)ia[r2] * NWORD + w16] : 0;
                #pragma unroll
                for (int r2 = 0; r2 < 8; ++r2) sup |= vv[r2];
            }
        }
        if (lane == 0) sh_kept[gh] = kept;
    }
    __syncthreads();

    const int kept = sh_kept[half];
    if (lt < K_PER) {
        int ob = (b * C_CLS + c) * K_PER + lt;
        if (lt < kept) {
            u64 k = key[half][swz(kept_t[half][lt])];
            ws_score[ob] = funord((u32)(k >> 32));
            ws_idx[ob]   = (N_BOX - 1) - (int)(u32)(k & 0xFFFFFFFFu);
        } else {
            ws_score[ob] = NEGF;
            ws_idx[ob]   = 0;
        }
    }
}

// ---------------------------------------------------------------------------
// Kernel 3: final top-300 per image (proven verbatim).
// ---------------------------------------------------------------------------
__global__ __launch_bounds__(1024) void final_topk(
        const float* __restrict__ ws_score,
        const int*   __restrict__ ws_idx,
        const float* __restrict__ boxes,    // [B, N, 1, 4]
        float* __restrict__ out)
{
    __shared__ u32 skey[NCAND];             // 32 KB
    __shared__ u32 hist4[256 * 4];          // 4 KB
    __shared__ u64 list[512];
    __shared__ int sh_sel;
    __shared__ u32 sh_need;
    __shared__ int sh_cnt, sh_valid;

    const int tid = threadIdx.x;
    const int b = blockIdx.x;
    const int base = b * NCAND;

    if (tid == 0) { sh_cnt = 0; sh_valid = 0; }
    for (int i = tid; i < NCAND; i += 1024)
        skey[i] = ford(ws_score[base + i]);
    if (tid < 512) list[tid] = 0;
    hist4[tid] = 0;
    __syncthreads();

    u64 prefix = 0;
    u32 need = K_TOT;
    const int rounds[6] = {7, 6, 5, 4, 1, 0};
    const int slot = tid & 3;

    for (int rd = 0; rd < 6; ++rd) {
        const int d = rounds[rd];
        for (int i = tid; i < NCAND; i += 1024) {
            u64 k = ((u64)skey[i] << 32) | (u32)(M_SEL - 1 - i);
            // d==7 guard: shift by 64 is UB (the round-3/4 crash)
            bool match = (d == 7) || (((k ^ prefix) >> (8 * (d + 1))) == 0);
            if (match)
                atomicAdd(&hist4[(((u32)(k >> (8 * d)) & 0xFFu) << 2) | slot], 1u);
        }
        __syncthreads();
        if (tid < 64) {
            const int l = tid;
            u32 h[4];
            #pragma unroll
            for (int q = 0; q < 4; ++q) {
                int bin = 4 * l + q;
                h[q] = hist4[bin * 4 + 0] + hist4[bin * 4 + 1]
                     + hist4[bin * 4 + 2] + hist4[bin * 4 + 3];
                hist4[bin * 4 + 0] = 0; hist4[bin * 4 + 1] = 0;
                hist4[bin * 4 + 2] = 0; hist4[bin * 4 + 3] = 0;
            }
            u32 s3 = h[3], s2 = h[2] + s3, s1 = h[1] + s2, s0 = h[0] + s1;
            u32 tot = s0, S = tot;
            #pragma unroll
            for (int off = 1; off < 64; off <<= 1) {
                u32 t = __shfl(S, (l + off) & 63);
                if (l + off < 64) S += t;
            }
            u32 T = S - tot;
            u32 sv0 = s0 + T, sv1 = s1 + T, sv2 = s2 + T, sv3 = s3 + T;
            if (sv0 >= need && sv1 < need) { sh_sel = 4*l;     sh_need = need - sv1; }
            if (sv1 >= need && sv2 < need) { sh_sel = 4*l + 1; sh_need = need - sv2; }
            if (sv2 >= need && sv3 < need) { sh_sel = 4*l + 2; sh_need = need - sv3; }
            if (sv3 >= need && T   < need) { sh_sel = 4*l + 3; sh_need = need - T;   }
        }
        __syncthreads();
        prefix |= ((u64)(u32)sh_sel) << (8 * d);
        need = sh_need;
        __syncthreads();
    }

    for (int i = tid; i < NCAND; i += 1024) {
        u64 k = ((u64)skey[i] << 32) | (u32)(M_SEL - 1 - i);
        if (k >= prefix) {
            int p = atomicAdd(&sh_cnt, 1);
            if (p < 512) list[p] = k;
        }
    }
    __syncthreads();

    // one-wave register bitonic sort of list[512], descending (pads 0 last)
    if (tid < 64) {
        const int l = tid;
        u64 e[8];
        #pragma unroll
        for (int q = 0; q < 8; ++q) e[q] = list[l * 8 + q];
        #define CE2(a, b, dd) { u64 _mx = (a) > (b) ? (a) : (b); \
                                u64 _mn = (a) > (b) ? (b) : (a); \
                                (a) = (dd) ? _mx : _mn; (b) = (dd) ? _mn : _mx; }
        CE2(e[0], e[1], true);  CE2(e[2], e[3], false);
        CE2(e[4], e[5], true);  CE2(e[6], e[7], false);
        CE2(e[0], e[2], true);  CE2(e[1], e[3], true);
        CE2(e[4], e[6], false); CE2(e[5], e[7], false);
        CE2(e[0], e[1], true);  CE2(e[2], e[3], true);
        CE2(e[4], e[5], false); CE2(e[6], e[7], false);
        for (int k = 8; k <= 512; k <<= 1) {
            const bool d = ((l & (k >> 3)) == 0);
            for (int j = k >> 1; j >= 8; j >>= 1) {
                const int dl = j >> 3;
                const bool upper = (l & dl) != 0;
                #pragma unroll
                for (int q = 0; q < 8; ++q) {
                    u64 pv = __shfl_xor(e[q], dl);
                    u64 mx = e[q] > pv ? e[q] : pv;
                    u64 mn = e[q] > pv ? pv : e[q];
                    e[q] = (d != upper) ? mx : mn;
                }
            }
            CE2(e[0], e[4], d); CE2(e[1], e[5], d);
            CE2(e[2], e[6], d); CE2(e[3], e[7], d);
            CE2(e[0], e[2], d); CE2(e[1], e[3], d);
            CE2(e[4], e[6], d); CE2(e[5], e[7], d);
            CE2(e[0], e[1], d); CE2(e[2], e[3], d);
            CE2(e[4], e[5], d); CE2(e[6], e[7], d);
        }
        #undef CE2
        #pragma unroll
        for (int q = 0; q < 8; ++q) list[l * 8 + q] = e[q];
    }
    __syncthreads();

    float* out_s = out;                         // [B,300]
    float* out_b = out + B_IMG * K_TOT;         // [B,300,4]
    float* out_c = out + B_IMG * K_TOT * 5;     // [B,300]
    float* out_n = out + B_IMG * K_TOT * 6;     // [B]

    for (int i = tid; i < K_TOT; i += 1024) {
        u64 k = list[i];
        float s = funord((u32)(k >> 32));
        int flat = (M_SEL - 1) - (int)(u32)(k & 0xFFFFFFFFu);
        bool valid = s > (-5e29f);              // top_s > NEG/2
        float os = 0.0f, oc = 0.0f;
        float4 ob = make_float4(0.0f, 0.0f, 0.0f, 0.0f);
        if (valid && flat < NCAND) {
            int cc = flat / K_PER;
            int n  = ws_idx[base + flat];
            float4 bb = ((const float4*)boxes)[b * N_BOX + n];
            os = s;
            oc = (float)cc;
            ob.x = fminf(fmaxf(bb.x, 0.0f), 1.0f);
            ob.y = fminf(fmaxf(bb.y, 0.0f), 1.0f);
            ob.z = fminf(fmaxf(bb.z, 0.0f), 1.0f);
            ob.w = fminf(fmaxf(bb.w, 0.0f), 1.0f);
            atomicAdd(&sh_valid, 1);
        }
        out_s[b * K_TOT + i] = os;
        ((float4*)out_b)[b * K_TOT + i] = ob;
        out_c[b * K_TOT + i] = oc;
    }
    __syncthreads();
    if (tid == 0) out_n[b] = (float)sh_valid;
}

extern "C" void kernel_launch(void* const* d_in, const int* in_sizes, int n_in,
                              void* d_out, int out_size, void* d_ws, size_t ws_size,
                              hipStream_t stream) {
    const float* scores = (const float*)d_in[0];   // [4,1024,80]
    const float* boxes  = (const float*)d_in[1];   // [4,1024,1,4]

    char* ws = (char*)d_ws;                        // 2,091,008 B (proven)
    float* scoresT  = (float*)(ws + OFF_SCOREST);
    u64*   masks    = (u64*)  (ws + OFF_MASKS);
    float* ws_score = (float*)(ws + OFF_WSCORE);
    int*   ws_idx   = (int*)  (ws + OFF_WSIDX);

    prep_kernel<<<dim3(256 + 1280), dim3(256), 0, stream>>>(scores, boxes, masks, scoresT);
    nms_classes<<<dim3(B_IMG * (C_CLS / 2)), dim3(512), 0, stream>>>(
        scoresT, masks, ws_score, ws_idx);
    final_topk<<<dim3(B_IMG), dim3(1024), 0, stream>>>(
        ws_score, ws_idx, boxes, (float*)d_out);
}

// Round 16
// 120.890 us; speedup vs baseline: 1.1665x; 1.1665x over previous
//
#include <hip/hip_runtime.h>
#include <stdint.h>

#define N_BOX 1024
#define C_CLS 80
#define B_IMG 4
#define K_PER 100
#define K_TOT 300
#define NEGF  (-1e30f)
#define NWORD 16                 // 1024 bits / 64
#define NCAND (C_CLS * K_PER)    // 8000 candidates per image
#define M_SEL 8192               // flat-index packing base for final top-k
#define KPAD  1088               // 1024 + 64 swizzle pad

// workspace layout (bytes) — 2,091,008 total (proven footprint)
#define OFF_SCOREST 0            // [B][C][N] f32          1,310,720
#define OFF_MASKS   1310720     // [B][N][NWORD] u64        524,288
#define OFF_WSCORE  1835008     // [B*C][K_PER] f32         128,000
#define OFF_WSIDX   1963008     // [B*C][K_PER] i32         128,000

typedef unsigned long long u64;
typedef unsigned int u32;

// LDS bank swizzle for u64 key array: bank16 rotates per 16-element group.
__device__ __forceinline__ int swz(int i) { return i + (i >> 4); }

// ---- monotone float <-> ordered-uint mapping (total order, bit-exact) ----
__device__ __forceinline__ u32 ford(float f) {
    u32 u = __float_as_uint(f);
    return (u & 0x80000000u) ? ~u : (u | 0x80000000u);
}
__device__ __forceinline__ float funord(u32 o) {
    u32 u = (o & 0x80000000u) ? (o ^ 0x80000000u) : ~o;
    return __uint_as_float(u);
}

// ---------------------------------------------------------------------------
// Kernel 1 (fused prep, proven verbatim): blocks [0,256) = IoU bitmask
// matrix (hoisted canonicalization); blocks [256,1536) = transpose.
// ---------------------------------------------------------------------------
__global__ __launch_bounds__(256) void prep_kernel(
        const float* __restrict__ scores,   // [B, N, C]
        const float* __restrict__ boxes,    // [B, N, 1, 4]
        u64*   __restrict__ masks,          // [B, N, NWORD]
        float* __restrict__ scoresT)        // [B, C, N]
{
    __shared__ float4 bx[N_BOX];            // canonical y1,x1,y2,x2 (16 KB)
    __shared__ float  ar[N_BOX];            // area (4 KB)
    const int tid = threadIdx.x;

    if (blockIdx.x < 256) {
        const int b  = blockIdx.x >> 6;
        const int rg = blockIdx.x & 63;
        for (int n = tid; n < N_BOX; n += 256) {
            float4 v = ((const float4*)boxes)[b * N_BOX + n];
            {
#pragma clang fp contract(off)
                float y1 = fminf(v.x, v.z), y2 = fmaxf(v.x, v.z);
                float x1 = fminf(v.y, v.w), x2 = fmaxf(v.y, v.w);
                bx[n] = make_float4(y1, x1, y2, x2);
                ar[n] = (y2 - y1) * (x2 - x1);
            }
        }
        __syncthreads();

        const int r = tid >> 4;
        const int w = tid & 15;
        const int i = rg * 16 + r;
        const float4 a = bx[i];
        const float area_a = ar[i];
        u64 m = 0;
        const int j0 = w * 64;
        for (int jj = 0; jj < 64; ++jj) {
            int j = j0 + jj;
            float4 q = bx[j];
            {
#pragma clang fp contract(off)
                float ih = fminf(a.z, q.z) - fmaxf(a.x, q.x); ih = fmaxf(ih, 0.0f);
                float iw = fminf(a.w, q.w) - fmaxf(a.y, q.y); iw = fmaxf(iw, 0.0f);
                float inter = ih * iw;
                float uni = fmaxf(area_a + ar[j] - inter, 1e-12f);
                if (j != i && (inter / uni) > 0.5f) m |= (1ull << jj);
            }
        }
        masks[((size_t)(b * N_BOX + i)) * NWORD + w] = m;
    } else {
        float* tile = (float*)bx;               // [16][17]
        const int t = blockIdx.x - 256;
        const int b  = t / 320;
        const int rm = t % 320;
        const int n0 = (rm / 5) * 16;
        const int c0 = (rm % 5) * 16;
        const int r = tid >> 4, cc = tid & 15;
        tile[r * 17 + cc] = scores[(size_t)(b * N_BOX + n0 + r) * C_CLS + c0 + cc];
        __syncthreads();
        scoresT[(size_t)(b * C_CLS + c0 + r) * N_BOX + n0 + cc] = tile[cc * 17 + r];
    }
}

// ---------------------------------------------------------------------------
// Kernel 2 (fused sort+greedy, r14 base + SW-pipelined prefetch): one block
// per (image, class-PAIR), 512 thr. Sort: proven register/shuffle bitonic
// (swizzled LDS). Greedy: kill-mask accept-only loop (r14 proven), with the
// NEXT window's 16 mask rows loaded into VGPRs BEFORE processing the current
// window — the global-load latency overlaps kill-build + accepts, and the
// ds_write (with its waitcnt) lands after the consume phase.
// ---------------------------------------------------------------------------
__global__ __launch_bounds__(512) void nms_classes(
        const float* __restrict__ scoresT,  // [B, C, N]
        const u64*   __restrict__ masks,    // [B, N, NWORD]
        float* __restrict__ ws_score,       // [B*C*K_PER]
        int*   __restrict__ ws_idx)         // [B*C*K_PER]
{
    __shared__ u64 key[2][KPAD];            // 17408 B (swizzled)
    __shared__ u64 rows[2][64][NWORD];      // 16384 B — per-half row cache
    __shared__ int kept_t[2][K_PER];
    __shared__ int sh_nvalid[2], sh_kept[2];

    const int tid  = threadIdx.x;
    const int half = tid >> 8;              // 0/1 = which class of the pair
    const int lt   = tid & 255;             // half-local thread id
    const int lane = tid & 63;
    const int b  = blockIdx.x / (C_CLS / 2);
    const int c  = (blockIdx.x % (C_CLS / 2)) * 2 + half;

    if (lt == 0) { sh_nvalid[half] = 0; sh_kept[half] = 0; }
    __syncthreads();

    // ---- load: thread lt owns elements v = lt*4+q (coalesced float4) ----
    u64 r[4];
    {
        const float4 s4 = ((const float4*)(scoresT + ((size_t)(b * C_CLS + c) << 10)))[lt];
        float sv[4] = {s4.x, s4.y, s4.z, s4.w};
        int lv = 0;
        #pragma unroll
        for (int q = 0; q < 4; ++q) {
            bool valid = sv[q] > 0.001f;               // SCORE_THR
            float s = valid ? sv[q] : NEGF;
            int v = lt * 4 + q;
            r[q] = ((u64)ford(s) << 32) | (u32)(N_BOX - 1 - v);  // stable ties
            lv += valid ? 1 : 0;
        }
        if (lv) atomicAdd(&sh_nvalid[half], lv);
    }

    // ---- register/shuffle bitonic sort, descending (proven network) ----
    #define CE(a, b, d) { u64 _mx = (a) > (b) ? (a) : (b); \
                          u64 _mn = (a) > (b) ? (b) : (a); \
                          (a) = (d) ? _mx : _mn; (b) = (d) ? _mn : _mx; }
    CE(r[0], r[1], true); CE(r[2], r[3], false);

    for (int k = 4; k <= N_BOX; k <<= 1) {
        const bool d = ((lt & (k >> 2)) == 0);
        for (int j = k >> 1; j > 0; j >>= 1) {
            if (j >= 256) {                          // cross-wave: LDS stage
                __syncthreads();
                #pragma unroll
                for (int q = 0; q < 4; ++q) key[half][swz(lt * 4 + q)] = r[q];
                __syncthreads();
                const bool upper = ((lt * 4) & j) != 0;
                #pragma unroll
                for (int q = 0; q < 4; ++q) {
                    u64 pv = key[half][swz((lt * 4 + q) ^ j)];
                    u64 mx = r[q] > pv ? r[q] : pv;
                    u64 mn = r[q] > pv ? pv : r[q];
                    r[q] = (d != upper) ? mx : mn;
                }
            } else if (j >= 4) {                     // intra-wave: shuffle
                const int dl = j >> 2;
                const bool upper = (lane & dl) != 0;
                #pragma unroll
                for (int q = 0; q < 4; ++q) {
                    u64 pv = __shfl_xor(r[q], dl);
                    u64 mx = r[q] > pv ? r[q] : pv;
                    u64 mn = r[q] > pv ? pv : r[q];
                    r[q] = (d != upper) ? mx : mn;
                }
            } else if (j == 2) {
                CE(r[0], r[2], d); CE(r[1], r[3], d);
            } else {
                CE(r[0], r[1], d); CE(r[2], r[3], d);
            }
        }
    }
    #undef CE

    __syncthreads();
    #pragma unroll
    for (int q = 0; q < 4; ++q) key[half][swz(lt * 4 + q)] = r[q];
    __syncthreads();

    // ---- kill-mask greedy w/ pipelined prefetch: wave 0 -> h0, 4 -> h1 ----
    const int wv = tid >> 6;
    if (wv == 0 || wv == 4) {
        const int gh = wv >> 2;
        const int w16 = lane & 15;
        const int sslot = lane >> 4;            // 0..3
        const u64* mrow = masks + (size_t)b * N_BOX * NWORD;
        const int nvalid = sh_nvalid[gh];
        const int nwin = (nvalid + 63) >> 6;    // windows actually populated
        u64 sup = 0;                            // lanes 0..15 hold words
        int kept = 0;

        // per-window candidate info (recomputed per window; cheap)
        // pipeline registers: next window's 16 rows held in VGPRs
        u64 pf[16];
        // prologue: issue window 0's loads
        {
            u64 kv0 = key[gh][swz(lane)];
            int idx0 = (N_BOX - 1) - (int)(u32)(kv0 & 0xFFFFFFFFu);
            #pragma unroll
            for (int p = 0; p < 16; ++p) {
                int rr = p * 4 + sslot;
                int ir = __shfl(idx0, rr);
                pf[p] = (rr < nvalid) ? mrow[(size_t)ir * NWORD + w16] : 0;
            }
        }

        for (int w = 0; w < nwin && kept < K_PER; ++w) {
            const int bt = w * 64;
            // commit the in-flight prefetch for THIS window to LDS
            #pragma unroll
            for (int p = 0; p < 16; ++p)
                rows[gh][p * 4 + sslot][w16] = pf[p];
            __builtin_amdgcn_wave_barrier();

            // issue NEXT window's loads into VGPRs (latency overlaps below)
            if (w + 1 < nwin) {
                u64 kvn = key[gh][swz(bt + 64 + lane)];
                int idxn = (N_BOX - 1) - (int)(u32)(kvn & 0xFFFFFFFFu);
                #pragma unroll
                for (int p = 0; p < 16; ++p) {
                    int rr = p * 4 + sslot;
                    int ir = __shfl(idxn, rr);
                    pf[p] = ((bt + 64 + rr) < nvalid)
                          ? mrow[(size_t)ir * NWORD + w16] : 0;
                }
            }

            // current window candidate info
            int t = bt + lane;
            bool in = t < nvalid;
            u64 kv = key[gh][swz(t & (N_BOX - 1))];
            int idx = (N_BOX - 1) - (int)(u32)(kv & 0xFFFFFFFFu);
            const int widx = idx >> 6, bidx = idx & 63;

            u64 supw = __shfl(sup, widx);
            u64 pending = __ballot(in && !((supw >> bidx) & 1ull));
            if (!pending) continue;

            // build per-lane kill mask (64 independent LDS reads, off-chain)
            u64 kill_mask = 0;
            #pragma unroll
            for (int rr = 0; rr < 64; ++rr) {
                u64 wj = rows[gh][rr][widx];
                kill_mask |= ((wj >> bidx) & 1ull) << rr;
            }

            // accept-only serial loop: pure VALU + ballot
            while (pending && kept < K_PER) {
                int t0 = __ffsll((long long)pending) - 1;      // wave-uniform
                if (lane == 0) kept_t[gh][kept] = bt + t0;
                kept++;
                if (lane < NWORD) sup |= rows[gh][t0][w16];    // off-chain
                bool kill = (kill_mask >> t0) & 1ull;
                pending &= ~(1ull << t0);
                pending &= ~__ballot(kill);
            }
        }
        if (lane == 0) sh_kept[gh] = kept;
    }
    __syncthreads();

    const int kept = sh_kept[half];
    if (lt < K_PER) {
        int ob = (b * C_CLS + c) * K_PER + lt;
        if (lt < kept) {
            u64 k = key[half][swz(kept_t[half][lt])];
            ws_score[ob] = funord((u32)(k >> 32));
            ws_idx[ob]   = (N_BOX - 1) - (int)(u32)(k & 0xFFFFFFFFu);
        } else {
            ws_score[ob] = NEGF;
            ws_idx[ob]   = 0;
        }
    }
}

// ---------------------------------------------------------------------------
// Kernel 3: final top-300 per image (proven verbatim).
// ---------------------------------------------------------------------------
__global__ __launch_bounds__(1024) void final_topk(
        const float* __restrict__ ws_score,
        const int*   __restrict__ ws_idx,
        const float* __restrict__ boxes,    // [B, N, 1, 4]
        float* __restrict__ out)
{
    __shared__ u32 skey[NCAND];             // 32 KB
    __shared__ u32 hist4[256 * 4];          // 4 KB
    __shared__ u64 list[512];
    __shared__ int sh_sel;
    __shared__ u32 sh_need;
    __shared__ int sh_cnt, sh_valid;

    const int tid = threadIdx.x;
    const int b = blockIdx.x;
    const int base = b * NCAND;

    if (tid == 0) { sh_cnt = 0; sh_valid = 0; }
    for (int i = tid; i < NCAND; i += 1024)
        skey[i] = ford(ws_score[base + i]);
    if (tid < 512) list[tid] = 0;
    hist4[tid] = 0;
    __syncthreads();

    u64 prefix = 0;
    u32 need = K_TOT;
    const int rounds[6] = {7, 6, 5, 4, 1, 0};
    const int slot = tid & 3;

    for (int rd = 0; rd < 6; ++rd) {
        const int d = rounds[rd];
        for (int i = tid; i < NCAND; i += 1024) {
            u64 k = ((u64)skey[i] << 32) | (u32)(M_SEL - 1 - i);
            // d==7 guard: shift by 64 is UB (the round-3/4 crash)
            bool match = (d == 7) || (((k ^ prefix) >> (8 * (d + 1))) == 0);
            if (match)
                atomicAdd(&hist4[(((u32)(k >> (8 * d)) & 0xFFu) << 2) | slot], 1u);
        }
        __syncthreads();
        if (tid < 64) {
            const int l = tid;
            u32 h[4];
            #pragma unroll
            for (int q = 0; q < 4; ++q) {
                int bin = 4 * l + q;
                h[q] = hist4[bin * 4 + 0] + hist4[bin * 4 + 1]
                     + hist4[bin * 4 + 2] + hist4[bin * 4 + 3];
                hist4[bin * 4 + 0] = 0; hist4[bin * 4 + 1] = 0;
                hist4[bin * 4 + 2] = 0; hist4[bin * 4 + 3] = 0;
            }
            u32 s3 = h[3], s2 = h[2] + s3, s1 = h[1] + s2, s0 = h[0] + s1;
            u32 tot = s0, S = tot;
            #pragma unroll
            for (int off = 1; off < 64; off <<= 1) {
                u32 t = __shfl(S, (l + off) & 63);
                if (l + off < 64) S += t;
            }
            u32 T = S - tot;
            u32 sv0 = s0 + T, sv1 = s1 + T, sv2 = s2 + T, sv3 = s3 + T;
            if (sv0 >= need && sv1 < need) { sh_sel = 4*l;     sh_need = need - sv1; }
            if (sv1 >= need && sv2 < need) { sh_sel = 4*l + 1; sh_need = need - sv2; }
            if (sv2 >= need && sv3 < need) { sh_sel = 4*l + 2; sh_need = need - sv3; }
            if (sv3 >= need && T   < need) { sh_sel = 4*l + 3; sh_need = need - T;   }
        }
        __syncthreads();
        prefix |= ((u64)(u32)sh_sel) << (8 * d);
        need = sh_need;
        __syncthreads();
    }

    for (int i = tid; i < NCAND; i += 1024) {
        u64 k = ((u64)skey[i] << 32) | (u32)(M_SEL - 1 - i);
        if (k >= prefix) {
            int p = atomicAdd(&sh_cnt, 1);
            if (p < 512) list[p] = k;
        }
    }
    __syncthreads();

    // one-wave register bitonic sort of list[512], descending (pads 0 last)
    if (tid < 64) {
        const int l = tid;
        u64 e[8];
        #pragma unroll
        for (int q = 0; q < 8; ++q) e[q] = list[l * 8 + q];
        #define CE2(a, b, dd) { u64 _mx = (a) > (b) ? (a) : (b); \
                                u64 _mn = (a) > (b) ? (b) : (a); \
                                (a) = (dd) ? _mx : _mn; (b) = (dd) ? _mn : _mx; }
        CE2(e[0], e[1], true);  CE2(e[2], e[3], false);
        CE2(e[4], e[5], true);  CE2(e[6], e[7], false);
        CE2(e[0], e[2], true);  CE2(e[1], e[3], true);
        CE2(e[4], e[6], false); CE2(e[5], e[7], false);
        CE2(e[0], e[1], true);  CE2(e[2], e[3], true);
        CE2(e[4], e[5], false); CE2(e[6], e[7], false);
        for (int k = 8; k <= 512; k <<= 1) {
            const bool d = ((l & (k >> 3)) == 0);
            for (int j = k >> 1; j >= 8; j >>= 1) {
                const int dl = j >> 3;
                const bool upper = (l & dl) != 0;
                #pragma unroll
                for (int q = 0; q < 8; ++q) {
                    u64 pv = __shfl_xor(e[q], dl);
                    u64 mx = e[q] > pv ? e[q] : pv;
                    u64 mn = e[q] > pv ? pv : e[q];
                    e[q] = (d != upper) ? mx : mn;
                }
            }
            CE2(e[0], e[4], d); CE2(e[1], e[5], d);
            CE2(e[2], e[6], d); CE2(e[3], e[7], d);
            CE2(e[0], e[2], d); CE2(e[1], e[3], d);
            CE2(e[4], e[6], d); CE2(e[5], e[7], d);
            CE2(e[0], e[1], d); CE2(e[2], e[3], d);
            CE2(e[4], e[5], d); CE2(e[6], e[7], d);
        }
        #undef CE2
        #pragma unroll
        for (int q = 0; q < 8; ++q) list[l * 8 + q] = e[q];
    }
    __syncthreads();

    float* out_s = out;                         // [B,300]
    float* out_b = out + B_IMG * K_TOT;         // [B,300,4]
    float* out_c = out + B_IMG * K_TOT * 5;     // [B,300]
    float* out_n = out + B_IMG * K_TOT * 6;     // [B]

    for (int i = tid; i < K_TOT; i += 1024) {
        u64 k = list[i];
        float s = funord((u32)(k >> 32));
        int flat = (M_SEL - 1) - (int)(u32)(k & 0xFFFFFFFFu);
        bool valid = s > (-5e29f);              // top_s > NEG/2
        float os = 0.0f, oc = 0.0f;
        float4 ob = make_float4(0.0f, 0.0f, 0.0f, 0.0f);
        if (valid && flat < NCAND) {
            int cc = flat / K_PER;
            int n  = ws_idx[base + flat];
            float4 bb = ((const float4*)boxes)[b * N_BOX + n];
            os = s;
            oc = (float)cc;
            ob.x = fminf(fmaxf(bb.x, 0.0f), 1.0f);
            ob.y = fminf(fmaxf(bb.y, 0.0f), 1.0f);
            ob.z = fminf(fmaxf(bb.z, 0.0f), 1.0f);
            ob.w = fminf(fmaxf(bb.w, 0.0f), 1.0f);
            atomicAdd(&sh_valid, 1);
        }
        out_s[b * K_TOT + i] = os;
        ((float4*)out_b)[b * K_TOT + i] = ob;
        out_c[b * K_TOT + i] = oc;
    }
    __syncthreads();
    if (tid == 0) out_n[b] = (float)sh_valid;
}

extern "C" void kernel_launch(void* const* d_in, const int* in_sizes, int n_in,
                              void* d_out, int out_size, void* d_ws, size_t ws_size,
                              hipStream_t stream) {
    const float* scores = (const float*)d_in[0];   // [4,1024,80]
    const float* boxes  = (const float*)d_in[1];   // [4,1024,1,4]

    char* ws = (char*)d_ws;                        // 2,091,008 B (proven)
    float* scoresT  = (float*)(ws + OFF_SCOREST);
    u64*   masks    = (u64*)  (ws + OFF_MASKS);
    float* ws_score = (float*)(ws + OFF_WSCORE);
    int*   ws_idx   = (int*)  (ws + OFF_WSIDX);

    prep_kernel<<<dim3(256 + 1280), dim3(256), 0, stream>>>(scores, boxes, masks, scoresT);
    nms_classes<<<dim3(B_IMG * (C_CLS / 2)), dim3(512), 0, stream>>>(
        scoresT, masks, ws_score, ws_idx);
    final_topk<<<dim3(B_IMG), dim3(1024), 0, stream>>>(
        ws_score, ws_idx, boxes, (float*)d_out);
}